// Round 1
// baseline (154.870 us; speedup 1.0000x reference)
//
#include <hip/hip_runtime.h>

// sub-exp disparity expectation:
//   d        = argmax_k beliefs[n,h,w,k]                 (first index wins ties)
//   win_k    = clamp(d + o, 0, K-1), o in [-3..3]        (duplicates at edges)
//   out      = sum(b[win_k] * win_k) / sum(b[win_k])
//
// Layout: K=128 is innermost/contiguous. One pixel per 32-lane half-wave;
// lane j loads float4 -> channels 4j..4j+3. 512 B/pixel, fully coalesced,
// 16 B/lane. Memory-bound: 503 MB in / 3.9 MB out.

#define KCH 128
#define SUPPORT 3

__global__ __launch_bounds__(256) void subexp_kernel(
    const float* __restrict__ beliefs, float* __restrict__ out, int npix) {
  int tid  = blockIdx.x * blockDim.x + threadIdx.x;
  int pix  = tid >> 5;          // 32 lanes per pixel
  int lane = tid & 31;
  if (pix >= npix) return;

  const float4 v4 =
      reinterpret_cast<const float4*>(beliefs)[(size_t)pix * 32 + lane];
  const float v0 = v4.x, v1 = v4.y, v2 = v4.z, v3 = v4.w;

  // ---- lane-local argmax (ascending k, strictly-greater replaces => first wins)
  float bm = v0;
  int   bi = lane * 4;
  if (v1 > bm) { bm = v1; bi = lane * 4 + 1; }
  if (v2 > bm) { bm = v2; bi = lane * 4 + 2; }
  if (v3 > bm) { bm = v3; bi = lane * 4 + 3; }

  // ---- cross-lane argmax over the 32-lane group (butterfly; tie -> lower idx)
  #pragma unroll
  for (int off = 16; off >= 1; off >>= 1) {
    float ov = __shfl_xor(bm, off, 32);
    int   oi = __shfl_xor(bi, off, 32);
    if (ov > bm || (ov == bm && oi < bi)) { bm = ov; bi = oi; }
  }
  const int d = bi;  // same value on all 32 lanes

  // ---- accumulate the 7 clamped window taps that live in this lane's quad.
  // Iterating the 7 offsets (not the 7 unique indices) preserves the
  // multiplicity that jnp's clip+take_along_axis produces at the boundaries.
  float w = 0.f, wk = 0.f;
  #pragma unroll
  for (int o = -SUPPORT; o <= SUPPORT; ++o) {
    int kk = d + o;
    kk = kk < 0 ? 0 : (kk > KCH - 1 ? KCH - 1 : kk);
    if ((kk >> 2) == lane) {
      const int r = kk & 3;
      // select chain (cndmask), NOT a runtime-indexed array (avoids scratch)
      const float v = (r == 0) ? v0 : (r == 1) ? v1 : (r == 2) ? v2 : v3;
      w  += v;
      wk += v * (float)kk;
    }
  }

  // ---- reduce (w, wk) across the 32-lane group
  #pragma unroll
  for (int off = 16; off >= 1; off >>= 1) {
    w  += __shfl_xor(w,  off, 32);
    wk += __shfl_xor(wk, off, 32);
  }

  if (lane == 0) out[pix] = wk / w;
}

extern "C" void kernel_launch(void* const* d_in, const int* in_sizes, int n_in,
                              void* d_out, int out_size, void* d_ws,
                              size_t ws_size, hipStream_t stream) {
  const float* beliefs = (const float*)d_in[0];
  float* out = (float*)d_out;

  const int npix = in_sizes[0] / KCH;  // 2*512*960 = 983040
  const int threads = 256;             // 8 pixels / block
  const long long total = (long long)npix * 32;
  const int blocks = (int)((total + threads - 1) / threads);

  subexp_kernel<<<blocks, threads, 0, stream>>>(beliefs, out, npix);
}

// Round 2
// 124.735 us; speedup vs baseline: 1.2416x; 1.2416x over previous
//
#include <hip/hip_runtime.h>

// sub-exp disparity expectation, K=128 innermost.
// One pixel per 32-lane group (2 pixels / wave64). Lane j loads float4 ->
// channels 4j..4j+3 (512 B/pixel, coalesced, 16 B/lane).
//
// R2 restructure (kill VALU-issue bound):
//  - group max: value-only DPP row_ror reduce (4 ops) + ds_swizzle xor16
//  - argmax index: ballot(bm==vmax) -> lowest lane = lowest channel (matches
//    np.argmax first-index), ds_bpermute its local index
//  - window: lanes 0..6 re-gather the 7 clamped taps from L1 (lines are hot),
//    then a 4-step DPP row-sum (taps live in one 16-lane row)

#define KCH 128

template <int CTRL>
__device__ __forceinline__ float dpp_ror_f(float x) {
  return __builtin_bit_cast(
      float, __builtin_amdgcn_update_dpp(0, __builtin_bit_cast(int, x), CTRL,
                                         0xF, 0xF, false));
}

__global__ __launch_bounds__(256) void subexp_kernel(
    const float* __restrict__ beliefs, float* __restrict__ out, int npix) {
  const int tid = blockIdx.x * blockDim.x + threadIdx.x;
  const int pix = tid >> 5;   // 32 lanes per pixel
  const int gl  = threadIdx.x & 31;  // lane within the 32-group
  if (pix >= npix) return;

  const float4 v4 =
      reinterpret_cast<const float4*>(beliefs)[(size_t)pix * 32 + gl];

  // ---- lane-local argmax over 4 channels (strict > => first index wins)
  float bm = v4.x;
  int   bi = gl * 4;
  if (v4.y > bm) { bm = v4.y; bi = gl * 4 + 1; }
  if (v4.z > bm) { bm = v4.z; bi = gl * 4 + 2; }
  if (v4.w > bm) { bm = v4.w; bi = gl * 4 + 3; }

  // ---- value-only max over the 32-group:
  // 4x DPP row_ror (ring all-reduce within 16-lane row), then xor16 swizzle
  float vm = bm;
  vm = fmaxf(vm, dpp_ror_f<0x121>(vm));  // ror:1
  vm = fmaxf(vm, dpp_ror_f<0x122>(vm));  // ror:2
  vm = fmaxf(vm, dpp_ror_f<0x124>(vm));  // ror:4
  vm = fmaxf(vm, dpp_ror_f<0x128>(vm));  // ror:8
  vm = fmaxf(vm, __builtin_bit_cast(
                     float, __builtin_amdgcn_ds_swizzle(
                                __builtin_bit_cast(int, vm), 0x401F)));  // ^16

  // ---- argmax = local index of the lowest lane holding vm.
  // Lanes are channel-ordered, so lowest lane == lowest channel (np tie rule).
  const unsigned long long mask = __ballot(bm == vm);
  const unsigned mlo = (unsigned)mask;
  const unsigned mhi = (unsigned)(mask >> 32);
  const int L = (threadIdx.x & 32) ? (32 + (int)__builtin_ctz(mhi))
                                   : (int)__builtin_ctz(mlo);
  const int d = __builtin_amdgcn_ds_bpermute(L << 2, bi);  // broadcast to group

  // ---- 7 clamped taps gathered by lanes 0..6 (L1-hot lines: just fetched)
  float w = 0.f, wk = 0.f;
  int kk = d + gl - 3;
  kk = kk < 0 ? 0 : (kk > KCH - 1 ? KCH - 1 : kk);
  if (gl < 7) {
    const float tv = beliefs[(size_t)pix * KCH + kk];
    w  = tv;
    wk = tv * (float)kk;
  }

  // ---- sum over the row (taps are in lanes 0..6 of a 16-lane row)
  w  += dpp_ror_f<0x121>(w);   wk += dpp_ror_f<0x121>(wk);
  w  += dpp_ror_f<0x122>(w);   wk += dpp_ror_f<0x122>(wk);
  w  += dpp_ror_f<0x124>(w);   wk += dpp_ror_f<0x124>(wk);
  w  += dpp_ror_f<0x128>(w);   wk += dpp_ror_f<0x128>(wk);

  if (gl == 0) out[pix] = wk / w;
}

extern "C" void kernel_launch(void* const* d_in, const int* in_sizes, int n_in,
                              void* d_out, int out_size, void* d_ws,
                              size_t ws_size, hipStream_t stream) {
  const float* beliefs = (const float*)d_in[0];
  float* out = (float*)d_out;

  const int npix = in_sizes[0] / KCH;  // 2*512*960 = 983040
  const int threads = 256;             // 8 pixels / block
  const long long total = (long long)npix * 32;
  const int blocks = (int)((total + threads - 1) / threads);

  subexp_kernel<<<blocks, threads, 0, stream>>>(beliefs, out, npix);
}

// Round 4
// 122.548 us; speedup vs baseline: 1.2638x; 1.0179x over previous
//
#include <hip/hip_runtime.h>

// sub-exp disparity expectation, K=128 innermost.
// Persistent 32-lane groups: grid = 2048 blocks (8 blocks/CU = 32 waves/CU),
// each group grid-strides over npix/16384 = 60 pixels with a depth-2 load
// pipeline so HBM loads stay in flight across the reduce/gather chain.
//
// Per pixel: lane j holds channels 4j..4j+3 (float4, 512 B/pixel coalesced).
//  - argmax: lane-local (strict >, first-index wins) + 4x DPP row_ror max +
//    ds_swizzle xor16; index via ballot lowest-lane (lanes channel-ordered)
//  - window: lanes 0..6 gather the 7 clamped taps (L1/L2-hot)
//  - (w,wk) sum: FULL 4-step ror ring (1,2,4,8). NOTE: row_ror:N delivers
//    lane (i-N) mod 16 -> a truncated ring is direction-sensitive (R3 bug:
//    3-step version left lane 0 with only its own tap, absmax 4.5).
//  - out = wk * rcp(w)   (rcp approx; |err| ~1e-3 << 2.54 threshold)

#define KCH 128

template <int CTRL>
__device__ __forceinline__ float dpp_ror_f(float x) {
  return __builtin_bit_cast(
      float, __builtin_amdgcn_update_dpp(0, __builtin_bit_cast(int, x), CTRL,
                                         0xF, 0xF, false));
}

__global__ __launch_bounds__(256) void subexp_kernel(
    const float* __restrict__ beliefs, float* __restrict__ out, int npix,
    int ngroups) {
  const int g0 = (blockIdx.x * blockDim.x + threadIdx.x) >> 5;
  const int gl = threadIdx.x & 31;
  if (g0 >= npix) return;
  const float4* __restrict__ b4 = reinterpret_cast<const float4*>(beliefs);

  // depth-2 prefetch pipeline
  float4 cur = b4[(size_t)g0 * 32 + gl];
  const int p1 = g0 + ngroups;
  float4 nx1 = (p1 < npix) ? b4[(size_t)p1 * 32 + gl] : cur;

  for (int p = g0; p < npix; p += ngroups) {
    const int p2 = p + 2 * ngroups;
    float4 nx2 = nx1;
    if (p2 < npix) nx2 = b4[(size_t)p2 * 32 + gl];

    // ---- lane-local argmax over 4 channels (strict > => first index wins)
    float bm = cur.x;
    int   bi = gl * 4;
    if (cur.y > bm) { bm = cur.y; bi = gl * 4 + 1; }
    if (cur.z > bm) { bm = cur.z; bi = gl * 4 + 2; }
    if (cur.w > bm) { bm = cur.w; bi = gl * 4 + 3; }

    // ---- value-only max over the 32-group (full ring: direction-agnostic)
    float vm = bm;
    vm = fmaxf(vm, dpp_ror_f<0x121>(vm));
    vm = fmaxf(vm, dpp_ror_f<0x122>(vm));
    vm = fmaxf(vm, dpp_ror_f<0x124>(vm));
    vm = fmaxf(vm, dpp_ror_f<0x128>(vm));
    vm = fmaxf(vm, __builtin_bit_cast(
                       float, __builtin_amdgcn_ds_swizzle(
                                  __builtin_bit_cast(int, vm), 0x401F)));

    // ---- argmax index: lowest lane holding vm (lanes are channel-ordered)
    const unsigned long long mask = __ballot(bm == vm);
    const int L = (threadIdx.x & 32)
                      ? (32 + (int)__builtin_ctz((unsigned)(mask >> 32)))
                      : (int)__builtin_ctz((unsigned)mask);
    const int d = __builtin_amdgcn_ds_bpermute(L << 2, bi);

    // ---- 7 clamped taps gathered by lanes 0..6 (lines are cache-hot)
    float w = 0.f, wk = 0.f;
    int kk = d + gl - 3;
    kk = kk < 0 ? 0 : (kk > KCH - 1 ? KCH - 1 : kk);
    if (gl < 7) {
      const float tv = beliefs[(size_t)p * KCH + kk];
      w  = tv;
      wk = tv * (float)kk;
    }

    // ---- FULL ring sum over the 16-lane row (taps in lanes 0..6)
    w += dpp_ror_f<0x121>(w);  wk += dpp_ror_f<0x121>(wk);
    w += dpp_ror_f<0x122>(w);  wk += dpp_ror_f<0x122>(wk);
    w += dpp_ror_f<0x124>(w);  wk += dpp_ror_f<0x124>(wk);
    w += dpp_ror_f<0x128>(w);  wk += dpp_ror_f<0x128>(wk);

    if (gl == 0) out[p] = wk * __builtin_amdgcn_rcpf(w);

    cur = nx1;
    nx1 = nx2;
  }
}

extern "C" void kernel_launch(void* const* d_in, const int* in_sizes, int n_in,
                              void* d_out, int out_size, void* d_ws,
                              size_t ws_size, hipStream_t stream) {
  const float* beliefs = (const float*)d_in[0];
  float* out = (float*)d_out;

  const int npix = in_sizes[0] / KCH;  // 2*512*960 = 983040
  const int threads = 256;             // 8 groups / block
  const int blocks = 2048;             // 8 blocks/CU -> 32 waves/CU, persistent
  const int ngroups = blocks * (threads / 32);  // 16384; 983040/16384 = 60 iters

  subexp_kernel<<<blocks, threads, 0, stream>>>(beliefs, out, npix, ngroups);
}

// Round 5
// 103.582 us; speedup vs baseline: 1.4951x; 1.1831x over previous
//
#include <hip/hip_runtime.h>

// sub-exp disparity expectation, K=128 innermost.
// Persistent 32-lane groups: grid = 2048 blocks (8/CU -> 32 waves/CU), each
// group does exactly 60 pixels (983040/16384) with a depth-2 load pipeline.
//
// R5: NO dependent gather. vmcnt retires in issue order, so R4's 7-tap
// re-load forced vmcnt(0) each iteration, draining the prefetches (that's
// why R2~R4 all sat at ~4.1 TB/s). Instead, compute window membership
// arithmetically from the register-resident float4:
//   m(c) = [c in [d-3, d+3]]  +  (c==0)*max(0,3-d)  +  (c==127)*max(0,d-124)
// which exactly reproduces clip(d+o,0,127) multiplicity at the boundaries.
// Only remaining VMEM = the prefetch loads -> waits are vmcnt(>=1), pipeline
// stays full.

#define KCH 128

template <int CTRL>
__device__ __forceinline__ float dpp_ror_f(float x) {
  return __builtin_bit_cast(
      float, __builtin_amdgcn_update_dpp(0, __builtin_bit_cast(int, x), CTRL,
                                         0xF, 0xF, false));
}

__device__ __forceinline__ float swz_xor16_f(float x) {
  return __builtin_bit_cast(
      float, __builtin_amdgcn_ds_swizzle(__builtin_bit_cast(int, x), 0x401F));
}

__global__ __launch_bounds__(256) void subexp_kernel(
    const float* __restrict__ beliefs, float* __restrict__ out, int npix,
    int ngroups) {
  const int g0 = (blockIdx.x * blockDim.x + threadIdx.x) >> 5;
  const int gl = threadIdx.x & 31;
  if (g0 >= npix) return;
  const float4* __restrict__ b4 = reinterpret_cast<const float4*>(beliefs);

  // per-lane channel constants (hoisted out of the loop)
  const float c0f = (float)(4 * gl), c1f = c0f + 1.f, c2f = c0f + 2.f,
              c3f = c0f + 3.f;

  // depth-2 prefetch pipeline (prologue loads are always in-bounds)
  float4 cur = b4[(size_t)g0 * 32 + gl];
  float4 nx1 = b4[(size_t)(g0 + ngroups) * 32 + gl];

  for (int p = g0; p < npix; p += ngroups) {
    // prefetch p+2 with clamped pixel index (branchless; last 2 iters re-read
    // pixel npix-1, value discarded by the rotate)
    int pc = p + 2 * ngroups;
    pc = pc < npix ? pc : npix - 1;
    const float4 nx2 = b4[(size_t)pc * 32 + gl];

    // ---- group max (value only): lane max4 -> 4x DPP ror ring -> xor16
    float vm = fmaxf(fmaxf(cur.x, cur.y), fmaxf(cur.z, cur.w));
    vm = fmaxf(vm, dpp_ror_f<0x121>(vm));
    vm = fmaxf(vm, dpp_ror_f<0x122>(vm));
    vm = fmaxf(vm, dpp_ror_f<0x124>(vm));
    vm = fmaxf(vm, dpp_ror_f<0x128>(vm));
    vm = fmaxf(vm, swz_xor16_f(vm));

    // ---- argmax index: lowest lane holding vm; lane-local first match.
    // Lanes/channels are ordered -> lowest lane + lowest r == np first-index.
    const int bi =
        4 * gl + (cur.x == vm ? 0 : cur.y == vm ? 1 : cur.z == vm ? 2 : 3);
    const unsigned long long mask = __ballot(vm == fmaxf(fmaxf(cur.x, cur.y),
                                                         fmaxf(cur.z, cur.w)));
    const int L = (threadIdx.x & 32)
                      ? (32 + (int)__builtin_ctz((unsigned)(mask >> 32)))
                      : (int)__builtin_ctz((unsigned)mask);
    const int d = __builtin_amdgcn_ds_bpermute(L << 2, bi);

    // ---- window multiplicities from registers (no re-load!)
    const int base = d - 3;
    const int c0 = 4 * gl;
    float m0 = ((unsigned)(c0 - base) <= 6u) ? 1.f : 0.f;
    float m1 = ((unsigned)(c0 + 1 - base) <= 6u) ? 1.f : 0.f;
    float m2 = ((unsigned)(c0 + 2 - base) <= 6u) ? 1.f : 0.f;
    float m3 = ((unsigned)(c0 + 3 - base) <= 6u) ? 1.f : 0.f;
    if (gl == 0)  m0 += fmaxf(0.f, (float)(3 - d));    // clamp pile-up at k=0
    if (gl == 31) m3 += fmaxf(0.f, (float)(d - 124));  // clamp pile-up at k=127
    float w  = m0 * cur.x + m1 * cur.y + m2 * cur.z + m3 * cur.w;
    float wk = m0 * cur.x * c0f + m1 * cur.y * c1f + m2 * cur.z * c2f +
               m3 * cur.w * c3f;

    // ---- full-ring sum over the 32-group (direction-agnostic: R3 lesson)
    w += dpp_ror_f<0x121>(w);  wk += dpp_ror_f<0x121>(wk);
    w += dpp_ror_f<0x122>(w);  wk += dpp_ror_f<0x122>(wk);
    w += dpp_ror_f<0x124>(w);  wk += dpp_ror_f<0x124>(wk);
    w += dpp_ror_f<0x128>(w);  wk += dpp_ror_f<0x128>(wk);
    w += swz_xor16_f(w);       wk += swz_xor16_f(wk);

    if (gl == 0) out[p] = wk * __builtin_amdgcn_rcpf(w);

    cur = nx1;
    nx1 = nx2;
  }
}

extern "C" void kernel_launch(void* const* d_in, const int* in_sizes, int n_in,
                              void* d_out, int out_size, void* d_ws,
                              size_t ws_size, hipStream_t stream) {
  const float* beliefs = (const float*)d_in[0];
  float* out = (float*)d_out;

  const int npix = in_sizes[0] / KCH;  // 2*512*960 = 983040
  const int threads = 256;             // 8 groups / block
  const int blocks = 2048;             // 8 blocks/CU -> 32 waves/CU, persistent
  const int ngroups = blocks * (threads / 32);  // 16384; 983040/16384 = 60

  subexp_kernel<<<blocks, threads, 0, stream>>>(beliefs, out, npix, ngroups);
}

// Round 6
// 97.843 us; speedup vs baseline: 1.5828x; 1.0587x over previous
//
#include <hip/hip_runtime.h>

// sub-exp disparity expectation, K=128 innermost.
// R6: 16-lane groups. Lane owns channels 8*gl..8*gl+7 (2x float4, 32 B/lane);
// one wave = 4 pixels = 2 KB per iteration. The 16-lane group IS a DPP row,
// so max- and sum-reduces are pure 4-step row_ror rings: the only DS op left
// is the ds_bpermute argmax-index broadcast (R5 had 4 lgkm-waited DS ops).
// Persistent grid: 2048 blocks, __launch_bounds__(256,8) pins VGPR<=64 so all
// blocks co-resident (32 waves/CU, no straggler tail); 32768 groups x 30
// iters exactly. Depth-1 prefetch (TLP across 8 waves/SIMD hides the rest).
//
//  - argmax: lane-local over 8 (strict-first), full ring max, ballot slice ->
//    lowest lane = lowest channel (np first-index), bpermute broadcast
//  - window: multiplicity arithmetic on register-resident values (no reload;
//    R5 lesson: a dependent VMEM op forces vmcnt(0) and kills the pipeline)
//  - boundary: lane 0 adds max(0,3-d) copies of k=0; lane 15 max(0,d-124) of
//    k=127 (exactly clip(d+o,0,127) multiplicities)
//  - full 4-step rings only (R3 lesson: truncated rings are direction-bound)

#define KCH 128

template <int CTRL>
__device__ __forceinline__ float dpp_ror_f(float x) {
  return __builtin_bit_cast(
      float, __builtin_amdgcn_update_dpp(0, __builtin_bit_cast(int, x), CTRL,
                                         0xF, 0xF, false));
}

__global__ __launch_bounds__(256, 8) void subexp_kernel(
    const float* __restrict__ beliefs, float* __restrict__ out, int npix,
    int ngroups) {
  const int lane = threadIdx.x & 63;
  const int gl   = lane & 15;  // lane within 16-group (== DPP row)
  const int g0   = (blockIdx.x * blockDim.x + threadIdx.x) >> 4;
  if (g0 >= npix) return;
  const float4* __restrict__ b4 = reinterpret_cast<const float4*>(beliefs);

  const int   slot  = gl * 2;          // float4 slot within the pixel row
  const int   c0    = 8 * gl;          // first channel owned by this lane
  const float cbase = (float)c0;

  // prologue: cur = pixel g0; prefetch next
  float4 curA = b4[(size_t)g0 * 32 + slot];
  float4 curB = b4[(size_t)g0 * 32 + slot + 1];
  int pn = g0 + ngroups;
  pn = pn < npix ? pn : npix - 1;
  float4 nxA = b4[(size_t)pn * 32 + slot];
  float4 nxB = b4[(size_t)pn * 32 + slot + 1];

  #pragma unroll 2
  for (int p = g0; p < npix; p += ngroups) {
    // issue next prefetch first (depth-1; clamped tail re-reads a hot line)
    int pc = p + 2 * ngroups;
    pc = pc < npix ? pc : npix - 1;
    const float4 pfA = b4[(size_t)pc * 32 + slot];
    const float4 pfB = b4[(size_t)pc * 32 + slot + 1];

    // ---- lane-local max over 8 channels
    const float bm =
        fmaxf(fmaxf(fmaxf(curA.x, curA.y), fmaxf(curA.z, curA.w)),
              fmaxf(fmaxf(curB.x, curB.y), fmaxf(curB.z, curB.w)));

    // ---- 16-lane full-ring max (row_ror 1,2,4,8)
    float vm = bm;
    vm = fmaxf(vm, dpp_ror_f<0x121>(vm));
    vm = fmaxf(vm, dpp_ror_f<0x122>(vm));
    vm = fmaxf(vm, dpp_ror_f<0x124>(vm));
    vm = fmaxf(vm, dpp_ror_f<0x128>(vm));

    // ---- lane-local first channel == vm (strict-first => np tie rule)
    const int r = (curA.x == vm) ? 0
                : (curA.y == vm) ? 1
                : (curA.z == vm) ? 2
                : (curA.w == vm) ? 3
                : (curB.x == vm) ? 4
                : (curB.y == vm) ? 5
                : (curB.z == vm) ? 6 : 7;
    const int bi = c0 + r;

    // ---- lowest lane of this 16-slice holding vm -> argmax index broadcast
    const unsigned long long mask = __ballot(bm == vm);
    const unsigned slice = (unsigned)(mask >> (lane & 48)) & 0xFFFFu;
    const int L = (lane & 48) + (int)__builtin_ctz(slice);
    const int d = __builtin_amdgcn_ds_bpermute(L << 2, bi);

    // ---- window from registers: sel = v if channel in [d-3, d+3]
    const int base = d - 3;
    float w = 0.f, wk = 0.f;
#define TAP(VV, RR)                                                     \
    {                                                                   \
      const float sv = ((unsigned)(c0 + RR - base) <= 6u) ? (VV) : 0.f; \
      w += sv;                                                          \
      wk = fmaf(sv, cbase + (float)RR, wk);                             \
    }
    TAP(curA.x, 0) TAP(curA.y, 1) TAP(curA.z, 2) TAP(curA.w, 3)
    TAP(curB.x, 4) TAP(curB.y, 5) TAP(curB.z, 6) TAP(curB.w, 7)
#undef TAP
    // boundary clamp pile-up: k=0 extra copies add 0 to wk
    if (gl == 0)  w += fmaxf(0.f, (float)(3 - d)) * curA.x;
    if (gl == 15) {
      const float e = fmaxf(0.f, (float)(d - 124)) * curB.w;
      w += e;
      wk = fmaf(e, 127.f, wk);
    }

    // ---- 16-lane full-ring sums
    w += dpp_ror_f<0x121>(w);  wk += dpp_ror_f<0x121>(wk);
    w += dpp_ror_f<0x122>(w);  wk += dpp_ror_f<0x122>(wk);
    w += dpp_ror_f<0x124>(w);  wk += dpp_ror_f<0x124>(wk);
    w += dpp_ror_f<0x128>(w);  wk += dpp_ror_f<0x128>(wk);

    if (gl == 0) out[p] = wk * __builtin_amdgcn_rcpf(w);

    // rotate pipeline registers
    curA = nxA; curB = nxB;
    nxA = pfA;  nxB = pfB;
  }
}

extern "C" void kernel_launch(void* const* d_in, const int* in_sizes, int n_in,
                              void* d_out, int out_size, void* d_ws,
                              size_t ws_size, hipStream_t stream) {
  const float* beliefs = (const float*)d_in[0];
  float* out = (float*)d_out;

  const int npix = in_sizes[0] / KCH;  // 2*512*960 = 983040
  const int threads = 256;             // 16 groups / block
  const int blocks = 2048;             // 8 blocks/CU co-resident (64-VGPR cap)
  const int ngroups = blocks * (threads / 16);  // 32768; 983040/32768 = 30

  subexp_kernel<<<blocks, threads, 0, stream>>>(beliefs, out, npix, ngroups);
}

// Round 7
// 96.868 us; speedup vs baseline: 1.5988x; 1.0101x over previous
//
#include <hip/hip_runtime.h>

// sub-exp disparity expectation, K=128 innermost.
// R7: R6 structure (16-lane groups, lane owns 8 channels, wave = 4 pixels =
// 2 KB/iter, persistent 2048 blocks @ launch_bounds(256,8), depth-1 prefetch)
// with three changes:
//  1) VALU-only argmax broadcast: 4-step DPP u32-min ring over
//     key = (bm==vm ? bi : BIG) replaces ballot/ctz/ds_bpermute.
//     -> ZERO DS ops in the loop, no lgkmcnt wait on the critical chain.
//  2) non-temporal loads (touch-once data; don't thrash L2).
//  3) exact pipeline epilogue: 983040/32768 = 30 iters/group exactly ->
//     28 pipelined + 2 peeled; no clamped tail prefetches (which would be
//     real HBM traffic under nt).
// Carried lessons: full 4-step rings only (R3); no dependent VMEM in the
// loop (R5: vmcnt retires in order, a dependent load drains the prefetch).

#define KCH 128

using f4 = __attribute__((ext_vector_type(4))) float;

template <int CTRL>
__device__ __forceinline__ float dpp_ror_f(float x) {
  return __builtin_bit_cast(
      float, __builtin_amdgcn_update_dpp(0, __builtin_bit_cast(int, x), CTRL,
                                         0xF, 0xF, false));
}
template <int CTRL>
__device__ __forceinline__ unsigned dpp_ror_u(unsigned x) {
  return (unsigned)__builtin_amdgcn_update_dpp(0, (int)x, CTRL, 0xF, 0xF,
                                               false);
}
__device__ __forceinline__ f4 ntload(const f4* p) {
  return __builtin_nontemporal_load(p);
}

__global__ __launch_bounds__(256, 8) void subexp_kernel(
    const float* __restrict__ beliefs, float* __restrict__ out, int npix,
    int ngroups) {
  const int gl = threadIdx.x & 15;  // lane within 16-group (== DPP row)
  const int g0 = (blockIdx.x * blockDim.x + threadIdx.x) >> 4;
  if (g0 >= npix) return;
  const f4* __restrict__ b4 = reinterpret_cast<const f4*>(beliefs);

  const int   slot  = gl * 2;   // f4 slot within the pixel row
  const int   c0    = 8 * gl;   // first channel owned by this lane
  const float cbase = (float)c0;

  auto process = [&](int p, const f4& A, const f4& B) {
    // ---- lane-local max over 8 channels
    const float bm = fmaxf(fmaxf(fmaxf(A.x, A.y), fmaxf(A.z, A.w)),
                           fmaxf(fmaxf(B.x, B.y), fmaxf(B.z, B.w)));

    // ---- 16-lane full-ring max (row_ror 1,2,4,8)
    float vm = bm;
    vm = fmaxf(vm, dpp_ror_f<0x121>(vm));
    vm = fmaxf(vm, dpp_ror_f<0x122>(vm));
    vm = fmaxf(vm, dpp_ror_f<0x124>(vm));
    vm = fmaxf(vm, dpp_ror_f<0x128>(vm));

    // ---- lane-local first channel == vm (strict-first => np tie rule)
    const int r = (A.x == vm) ? 0
                : (A.y == vm) ? 1
                : (A.z == vm) ? 2
                : (A.w == vm) ? 3
                : (B.x == vm) ? 4
                : (B.y == vm) ? 5
                : (B.z == vm) ? 6 : 7;

    // ---- VALU-only argmax broadcast: min bi among lanes holding vm
    unsigned key = (bm == vm) ? (unsigned)(c0 + r) : 0x7FFFFFFFu;
    key = min(key, dpp_ror_u<0x121>(key));
    key = min(key, dpp_ror_u<0x122>(key));
    key = min(key, dpp_ror_u<0x124>(key));
    key = min(key, dpp_ror_u<0x128>(key));
    const int d = (int)key;  // np.argmax, broadcast to all 16 lanes

    // ---- window from registers: sel = v if channel in [d-3, d+3]
    const int base = d - 3;
    float w = 0.f, wk = 0.f;
#define TAP(VV, RR)                                                     \
    {                                                                   \
      const float sv = ((unsigned)(c0 + RR - base) <= 6u) ? (VV) : 0.f; \
      w += sv;                                                          \
      wk = fmaf(sv, cbase + (float)RR, wk);                             \
    }
    TAP(A.x, 0) TAP(A.y, 1) TAP(A.z, 2) TAP(A.w, 3)
    TAP(B.x, 4) TAP(B.y, 5) TAP(B.z, 6) TAP(B.w, 7)
#undef TAP
    // boundary clamp pile-up (k=0 copies add 0 to wk)
    if (gl == 0)  w += fmaxf(0.f, (float)(3 - d)) * A.x;
    if (gl == 15) {
      const float e = fmaxf(0.f, (float)(d - 124)) * B.w;
      w += e;
      wk = fmaf(e, 127.f, wk);
    }

    // ---- 16-lane full-ring sums (full ring: direction-agnostic, R3 lesson)
    w += dpp_ror_f<0x121>(w);  wk += dpp_ror_f<0x121>(wk);
    w += dpp_ror_f<0x122>(w);  wk += dpp_ror_f<0x122>(wk);
    w += dpp_ror_f<0x124>(w);  wk += dpp_ror_f<0x124>(wk);
    w += dpp_ror_f<0x128>(w);  wk += dpp_ror_f<0x128>(wk);

    if (gl == 0) out[p] = wk * __builtin_amdgcn_rcpf(w);
  };

  // prologue: pixel g0 + prefetch g0+ngroups (both always valid: niter >= 2)
  f4 curA = ntload(&b4[(size_t)g0 * 32 + slot]);
  f4 curB = ntload(&b4[(size_t)g0 * 32 + slot + 1]);
  f4 nxA  = ntload(&b4[(size_t)(g0 + ngroups) * 32 + slot]);
  f4 nxB  = ntload(&b4[(size_t)(g0 + ngroups) * 32 + slot + 1]);

  const int niter = npix / ngroups;  // 983040/32768 = 30 (exact)
  int p = g0;
  #pragma unroll 2
  for (int i = 0; i < niter - 2; ++i) {
    const f4 pfA = ntload(&b4[(size_t)(p + 2 * ngroups) * 32 + slot]);
    const f4 pfB = ntload(&b4[(size_t)(p + 2 * ngroups) * 32 + slot + 1]);
    process(p, curA, curB);
    curA = nxA; curB = nxB;
    nxA = pfA;  nxB = pfB;
    p += ngroups;
  }
  process(p, curA, curB);
  p += ngroups;
  process(p, nxA, nxB);
}

extern "C" void kernel_launch(void* const* d_in, const int* in_sizes, int n_in,
                              void* d_out, int out_size, void* d_ws,
                              size_t ws_size, hipStream_t stream) {
  const float* beliefs = (const float*)d_in[0];
  float* out = (float*)d_out;

  const int npix = in_sizes[0] / KCH;  // 2*512*960 = 983040
  const int threads = 256;             // 16 groups / block
  const int blocks = 2048;             // 8 blocks/CU co-resident (64-VGPR cap)
  const int ngroups = blocks * (threads / 16);  // 32768; npix/ngroups = 30

  subexp_kernel<<<blocks, threads, 0, stream>>>(beliefs, out, npix, ngroups);
}

// Round 8
// 86.692 us; speedup vs baseline: 1.7864x; 1.1174x over previous
//
#include <hip/hip_runtime.h>

// sub-exp disparity expectation, K=128 innermost.
// R8: R7 structure (16-lane groups, persistent 2048 blocks @ lb(256,8),
// depth-2-in-flight prefetch, VALU-only reduces, nt loads, exact epilogue)
// with ONE change: per-instruction CONTIGUOUS slots.
//   load A: slot gl    -> channels 4gl..4gl+3     (group bytes [0,256))
//   load B: slot 16+gl -> channels 64+4gl..64+4gl+3 (group bytes [256,512))
// R6/R7 used slots {2gl, 2gl+1}: 16 B per lane at stride 32 B -> every 64-B
// sector half-covered per instruction and re-requested by the second load
// (2x sector/tag traffic). Copy ubench (6.3 TB/s) is per-instr contiguous.
// Channel scatter is absorbed arithmetically: membership per quad (bases
// cA=4gl, cB=64+4gl); lane-local first-match A-then-B is ascending; u32-min
// ring over channel indices = np first-index argmax regardless of layout.
// Carried: full rings only (R3); no dependent VMEM in loop (R5).

#define KCH 128

using f4 = __attribute__((ext_vector_type(4))) float;

template <int CTRL>
__device__ __forceinline__ float dpp_ror_f(float x) {
  return __builtin_bit_cast(
      float, __builtin_amdgcn_update_dpp(0, __builtin_bit_cast(int, x), CTRL,
                                         0xF, 0xF, false));
}
template <int CTRL>
__device__ __forceinline__ unsigned dpp_ror_u(unsigned x) {
  return (unsigned)__builtin_amdgcn_update_dpp(0, (int)x, CTRL, 0xF, 0xF,
                                               false);
}
__device__ __forceinline__ f4 ntload(const f4* p) {
  return __builtin_nontemporal_load(p);
}

__global__ __launch_bounds__(256, 8) void subexp_kernel(
    const float* __restrict__ beliefs, float* __restrict__ out, int npix,
    int ngroups) {
  const int gl = threadIdx.x & 15;  // lane within 16-group (== DPP row)
  const int g0 = (blockIdx.x * blockDim.x + threadIdx.x) >> 4;
  if (g0 >= npix) return;
  const f4* __restrict__ b4 = reinterpret_cast<const f4*>(beliefs);

  const int   slotA = gl;        // contiguous 256 B per group per instruction
  const int   slotB = 16 + gl;
  const int   cA    = 4 * gl;    // channels of quad A
  const int   cB    = 64 + 4 * gl;  // channels of quad B
  const float cAf   = (float)cA;
  const float cBf   = (float)cB;

  auto process = [&](int p, const f4& A, const f4& B) {
    // ---- lane-local max over 8 channels
    const float bm = fmaxf(fmaxf(fmaxf(A.x, A.y), fmaxf(A.z, A.w)),
                           fmaxf(fmaxf(B.x, B.y), fmaxf(B.z, B.w)));

    // ---- 16-lane full-ring max (row_ror 1,2,4,8)
    float vm = bm;
    vm = fmaxf(vm, dpp_ror_f<0x121>(vm));
    vm = fmaxf(vm, dpp_ror_f<0x122>(vm));
    vm = fmaxf(vm, dpp_ror_f<0x124>(vm));
    vm = fmaxf(vm, dpp_ror_f<0x128>(vm));

    // ---- lane-local first channel == vm (A quad before B quad: ascending)
    int bi;
    if      (A.x == vm) bi = cA + 0;
    else if (A.y == vm) bi = cA + 1;
    else if (A.z == vm) bi = cA + 2;
    else if (A.w == vm) bi = cA + 3;
    else if (B.x == vm) bi = cB + 0;
    else if (B.y == vm) bi = cB + 1;
    else if (B.z == vm) bi = cB + 2;
    else                bi = cB + 3;

    // ---- VALU-only argmax broadcast: min channel among lanes holding vm
    unsigned key = (bm == vm) ? (unsigned)bi : 0x7FFFFFFFu;
    key = min(key, dpp_ror_u<0x121>(key));
    key = min(key, dpp_ror_u<0x122>(key));
    key = min(key, dpp_ror_u<0x124>(key));
    key = min(key, dpp_ror_u<0x128>(key));
    const int d = (int)key;  // np.argmax (first-index), on all 16 lanes

    // ---- window from registers: sel = v if channel in [d-3, d+3]
    const int base = d - 3;
    float w = 0.f, wk = 0.f;
#define TAP(VV, CC, CF, RR)                                              \
    {                                                                    \
      const float sv = ((unsigned)((CC) + RR - base) <= 6u) ? (VV) : 0.f;\
      w += sv;                                                           \
      wk = fmaf(sv, (CF) + (float)RR, wk);                               \
    }
    TAP(A.x, cA, cAf, 0) TAP(A.y, cA, cAf, 1)
    TAP(A.z, cA, cAf, 2) TAP(A.w, cA, cAf, 3)
    TAP(B.x, cB, cBf, 0) TAP(B.y, cB, cBf, 1)
    TAP(B.z, cB, cBf, 2) TAP(B.w, cB, cBf, 3)
#undef TAP
    // boundary clamp pile-up (k=0 copies add 0 to wk)
    if (gl == 0)  w += fmaxf(0.f, (float)(3 - d)) * A.x;   // channel 0
    if (gl == 15) {
      const float e = fmaxf(0.f, (float)(d - 124)) * B.w;  // channel 127
      w += e;
      wk = fmaf(e, 127.f, wk);
    }

    // ---- 16-lane full-ring sums (direction-agnostic, R3 lesson)
    w += dpp_ror_f<0x121>(w);  wk += dpp_ror_f<0x121>(wk);
    w += dpp_ror_f<0x122>(w);  wk += dpp_ror_f<0x122>(wk);
    w += dpp_ror_f<0x124>(w);  wk += dpp_ror_f<0x124>(wk);
    w += dpp_ror_f<0x128>(w);  wk += dpp_ror_f<0x128>(wk);

    if (gl == 0) out[p] = wk * __builtin_amdgcn_rcpf(w);
  };

  // prologue: pixel g0 + prefetch g0+ngroups (both valid: niter = 30)
  f4 curA = ntload(&b4[(size_t)g0 * 32 + slotA]);
  f4 curB = ntload(&b4[(size_t)g0 * 32 + slotB]);
  f4 nxA  = ntload(&b4[(size_t)(g0 + ngroups) * 32 + slotA]);
  f4 nxB  = ntload(&b4[(size_t)(g0 + ngroups) * 32 + slotB]);

  const int niter = npix / ngroups;  // 983040/32768 = 30 (exact)
  int p = g0;
  #pragma unroll 2
  for (int i = 0; i < niter - 2; ++i) {
    const f4 pfA = ntload(&b4[(size_t)(p + 2 * ngroups) * 32 + slotA]);
    const f4 pfB = ntload(&b4[(size_t)(p + 2 * ngroups) * 32 + slotB]);
    process(p, curA, curB);
    curA = nxA; curB = nxB;
    nxA = pfA;  nxB = pfB;
    p += ngroups;
  }
  process(p, curA, curB);
  p += ngroups;
  process(p, nxA, nxB);
}

extern "C" void kernel_launch(void* const* d_in, const int* in_sizes, int n_in,
                              void* d_out, int out_size, void* d_ws,
                              size_t ws_size, hipStream_t stream) {
  const float* beliefs = (const float*)d_in[0];
  float* out = (float*)d_out;

  const int npix = in_sizes[0] / KCH;  // 2*512*960 = 983040
  const int threads = 256;             // 16 groups / block
  const int blocks = 2048;             // 8 blocks/CU co-resident (64-VGPR cap)
  const int ngroups = blocks * (threads / 16);  // 32768; npix/ngroups = 30

  subexp_kernel<<<blocks, threads, 0, stream>>>(beliefs, out, npix, ngroups);
}